// Round 1
// baseline (5782.906 us; speedup 1.0000x reference)
//
#include <hip/hip_runtime.h>

// Problem constants
#define N_ROWS   131072
#define D_IN     512
#define D_H      128
#define K_CODES  256
#define R_TILE   8        // rows per block
#define NTHREADS 256

// LDS row pad for the [8][128] latent/restored tiles (132 keeps 16B alignment)
#define LP 132

__global__ __launch_bounds__(NTHREADS, 2) void rqvae_main(
    const float* __restrict__ emb,
    const float* __restrict__ Wenc,   // [128][512]
    const float* __restrict__ Wdec,   // [512][128]
    const float* __restrict__ cb0,    // [256][128]
    const float* __restrict__ cb1,
    const float* __restrict__ cb2,
    float* __restrict__ acc_rq,
    float* __restrict__ acc_recon,
    int* __restrict__ used)           // [3][256]
{
    __shared__ float s_emb[R_TILE * D_IN];   // 16 KB
    __shared__ float s_lat[R_TILE * LP];     // remainder tile
    __shared__ float s_res[R_TILE * LP];     // restored tile
    __shared__ float s_stage[8192];          // 32 KB staging (WencT / cbT / WdecT chunks)
    __shared__ float s_rv[4 * 8];
    __shared__ int   s_ri[4 * 8];
    __shared__ int   s_idx8[8];
    __shared__ float s_red[8];

    const int tid = threadIdx.x;
    const long rowBase = (long)blockIdx.x * R_TILE;

    // ---- Phase 0: load embedding tile (coalesced float4) ----
    {
        const float4* g = (const float4*)(emb + rowBase * D_IN);
        float4* s = (float4*)s_emb;
        #pragma unroll
        for (int i = 0; i < 4; ++i) s[tid + i * NTHREADS] = g[tid + i * NTHREADS];
    }

    // ---- Phase 1: latent tile = emb_tile @ Wenc.T ----
    // thread t: h = t&127, row-group rg = t>>7 handles rows rg*4..rg*4+3
    {
        const int h  = tid & 127;
        const int rg = tid >> 7;
        float lat_acc[4] = {0.f, 0.f, 0.f, 0.f};
        for (int c = 0; c < 16; ++c) {
            const int d0 = c * 32;
            __syncthreads();
            // stage WencT chunk [32 d][128 h], bank-swizzled
            for (int i = tid; i < 4096; i += NTHREADS) {
                const int hh = i >> 5, j = i & 31;
                s_stage[j * 128 + ((hh + j) & 127)] = Wenc[hh * D_IN + d0 + j];
            }
            __syncthreads();
            #pragma unroll
            for (int j = 0; j < 32; j += 4) {
                const float w0 = s_stage[(j+0)*128 + ((h+j+0)&127)];
                const float w1 = s_stage[(j+1)*128 + ((h+j+1)&127)];
                const float w2 = s_stage[(j+2)*128 + ((h+j+2)&127)];
                const float w3 = s_stage[(j+3)*128 + ((h+j+3)&127)];
                #pragma unroll
                for (int q = 0; q < 4; ++q) {
                    const float4 e4 = *(const float4*)&s_emb[(rg*4+q)*D_IN + d0 + j];
                    lat_acc[q] += w0*e4.x + w1*e4.y + w2*e4.z + w3*e4.w;
                }
            }
        }
        __syncthreads();
        #pragma unroll
        for (int q = 0; q < 4; ++q) {
            s_lat[(rg*4+q)*LP + h] = lat_acc[q];
            s_res[(rg*4+q)*LP + h] = 0.0f;
        }
    }

    // ---- Phase 2: three RQ stages ----
    float local_rq = 0.0f;
    const float* cbs[3] = {cb0, cb1, cb2};
    for (int t = 0; t < 3; ++t) {
        const float* __restrict__ cb = cbs[t];
        // scores: thread k = tid computes s_k = r.c_k - 0.5*||c_k||^2 for 8 rows
        float sc[8] = {0.f,0.f,0.f,0.f,0.f,0.f,0.f,0.f};
        float cn = 0.0f;
        for (int c = 0; c < 4; ++c) {
            const int d0 = c * 32;
            __syncthreads();
            // stage cbT chunk [32 d][256 k], bank-swizzled
            for (int i = tid; i < 8192; i += NTHREADS) {
                const int k2 = i >> 5, j = i & 31;
                s_stage[j * 256 + ((k2 + j) & 255)] = cb[k2 * D_H + d0 + j];
            }
            __syncthreads();
            #pragma unroll
            for (int j = 0; j < 32; j += 4) {
                const float c0 = s_stage[(j+0)*256 + ((tid+j+0)&255)];
                const float c1 = s_stage[(j+1)*256 + ((tid+j+1)&255)];
                const float c2 = s_stage[(j+2)*256 + ((tid+j+2)&255)];
                const float c3 = s_stage[(j+3)*256 + ((tid+j+3)&255)];
                cn += c0*c0 + c1*c1 + c2*c2 + c3*c3;
                #pragma unroll
                for (int rr = 0; rr < 8; ++rr) {
                    const float4 r4 = *(const float4*)&s_lat[rr*LP + d0 + j];
                    sc[rr] += c0*r4.x + c1*r4.y + c2*r4.z + c3*r4.w;
                }
            }
        }
        #pragma unroll
        for (int rr = 0; rr < 8; ++rr) sc[rr] -= 0.5f * cn;

        // per-wave argmax (tie -> lowest index, matches jnp.argmin-first semantics)
        float v[8]; int ix[8];
        #pragma unroll
        for (int rr = 0; rr < 8; ++rr) { v[rr] = sc[rr]; ix[rr] = tid; }
        #pragma unroll
        for (int off = 32; off >= 1; off >>= 1) {
            #pragma unroll
            for (int rr = 0; rr < 8; ++rr) {
                const float ov = __shfl_down(v[rr], off);
                const int   oi = __shfl_down(ix[rr], off);
                if (ov > v[rr] || (ov == v[rr] && oi < ix[rr])) { v[rr] = ov; ix[rr] = oi; }
            }
        }
        if ((tid & 63) == 0) {
            const int w = tid >> 6;
            #pragma unroll
            for (int rr = 0; rr < 8; ++rr) { s_rv[w*8+rr] = v[rr]; s_ri[w*8+rr] = ix[rr]; }
        }
        __syncthreads();
        if (tid < 8) {
            float bv = s_rv[tid]; int bi = s_ri[tid];
            #pragma unroll
            for (int w = 1; w < 4; ++w) {
                const float wv = s_rv[w*8+tid]; const int wi = s_ri[w*8+tid];
                if (wv > bv || (wv == bv && wi < bi)) { bv = wv; bi = wi; }
            }
            s_idx8[tid] = bi;
            used[t * K_CODES + bi] = 1;
        }
        __syncthreads();
        // update remainder/restored; accumulate 1.25-scaled-later rq sum
        #pragma unroll
        for (int i2 = 0; i2 < 4; ++i2) {
            const int ii = tid + i2 * NTHREADS;
            const int rr = ii >> 7, d = ii & 127;
            const float cv = cb[s_idx8[rr] * D_H + d];
            s_res[rr*LP + d] += cv;
            const float nl = s_lat[rr*LP + d] - cv;
            s_lat[rr*LP + d] = nl;
            local_rq += nl * nl;
        }
    }

    // ---- Phase 3: recon = restored @ Wdec.T, compare to emb ----
    float local_recon = 0.0f;
    {
        const int j0 = tid, j1 = tid + 256;
        float a0[8] = {0.f,0.f,0.f,0.f,0.f,0.f,0.f,0.f};
        float a1[8] = {0.f,0.f,0.f,0.f,0.f,0.f,0.f,0.f};
        for (int c = 0; c < 8; ++c) {
            const int h0 = c * 16;
            __syncthreads();
            // stage WdecT chunk [16 h][512 j], bank-swizzled
            for (int i = tid; i < 8192; i += NTHREADS) {
                const int jj = i >> 4, hh = i & 15;
                s_stage[hh * 512 + ((jj + hh) & 511)] = Wdec[jj * D_H + h0 + hh];
            }
            __syncthreads();
            #pragma unroll
            for (int hh = 0; hh < 16; hh += 4) {
                const float w00 = s_stage[(hh+0)*512 + ((j0+hh+0)&511)];
                const float w01 = s_stage[(hh+1)*512 + ((j0+hh+1)&511)];
                const float w02 = s_stage[(hh+2)*512 + ((j0+hh+2)&511)];
                const float w03 = s_stage[(hh+3)*512 + ((j0+hh+3)&511)];
                const float w10 = s_stage[(hh+0)*512 + ((j1+hh+0)&511)];
                const float w11 = s_stage[(hh+1)*512 + ((j1+hh+1)&511)];
                const float w12 = s_stage[(hh+2)*512 + ((j1+hh+2)&511)];
                const float w13 = s_stage[(hh+3)*512 + ((j1+hh+3)&511)];
                #pragma unroll
                for (int rr = 0; rr < 8; ++rr) {
                    const float4 r4 = *(const float4*)&s_res[rr*LP + h0 + hh];
                    a0[rr] += w00*r4.x + w01*r4.y + w02*r4.z + w03*r4.w;
                    a1[rr] += w10*r4.x + w11*r4.y + w12*r4.z + w13*r4.w;
                }
            }
        }
        #pragma unroll
        for (int rr = 0; rr < 8; ++rr) {
            const float d0v = a0[rr] - s_emb[rr*D_IN + j0];
            const float d1v = a1[rr] - s_emb[rr*D_IN + j1];
            local_recon += d0v*d0v + d1v*d1v;
        }
    }

    // ---- block reduce partials, one atomic each ----
    float r1 = local_rq, r2 = local_recon;
    #pragma unroll
    for (int off = 32; off >= 1; off >>= 1) {
        r1 += __shfl_down(r1, off);
        r2 += __shfl_down(r2, off);
    }
    __syncthreads();
    if ((tid & 63) == 0) { s_red[(tid>>6)*2] = r1; s_red[(tid>>6)*2+1] = r2; }
    __syncthreads();
    if (tid == 0) {
        atomicAdd(acc_rq,    s_red[0] + s_red[2] + s_red[4] + s_red[6]);
        atomicAdd(acc_recon, s_red[1] + s_red[3] + s_red[5] + s_red[7]);
    }
}

__global__ void rqvae_finalize(const float* __restrict__ acc,
                               const int* __restrict__ used,
                               float* __restrict__ out)
{
    __shared__ int s_sum[4];
    const int tid = threadIdx.x;
    for (int t = 0; t < 3; ++t) {
        int v = (used[t * K_CODES + tid] != 0) ? 1 : 0;
        #pragma unroll
        for (int off = 32; off >= 1; off >>= 1) v += __shfl_down(v, off);
        if ((tid & 63) == 0) s_sum[tid >> 6] = v;
        __syncthreads();
        if (tid == 0) out[3 + t] = (float)(s_sum[0] + s_sum[1] + s_sum[2] + s_sum[3]);
        __syncthreads();
    }
    if (tid == 0) {
        const float rq    = 1.25f * acc[0] / ((float)N_ROWS * 128.0f);
        const float recon =         acc[1] / ((float)N_ROWS * 512.0f);
        out[0] = recon + rq;
        out[1] = recon;
        out[2] = rq;
    }
}

extern "C" void kernel_launch(void* const* d_in, const int* in_sizes, int n_in,
                              void* d_out, int out_size, void* d_ws, size_t ws_size,
                              hipStream_t stream) {
    const float* emb  = (const float*)d_in[0];
    const float* Wenc = (const float*)d_in[1];
    const float* Wdec = (const float*)d_in[2];
    const float* cb0  = (const float*)d_in[3];
    const float* cb1  = (const float*)d_in[4];
    const float* cb2  = (const float*)d_in[5];

    float* ws_f = (float*)d_ws;          // [0]=rq_sum, [1]=recon_sum
    int*   used = (int*)d_ws + 16;       // 3*256 flags

    hipMemsetAsync(d_ws, 0, (16 + 3 * K_CODES) * sizeof(int), stream);
    rqvae_main<<<N_ROWS / R_TILE, NTHREADS, 0, stream>>>(
        emb, Wenc, Wdec, cb0, cb1, cb2, ws_f + 0, ws_f + 1, used);
    rqvae_finalize<<<1, NTHREADS, 0, stream>>>(ws_f, used, (float*)d_out);
}

// Round 2
// 747.531 us; speedup vs baseline: 7.7360x; 7.7360x over previous
//
#include <hip/hip_runtime.h>

#define N_ROWS   131072
#define D_IN     512
#define D_H      128
#define K_CODES  256
#define NT       256          // 4 waves
#define RPB      128          // rows per block (32 per wave: 2 x 16-row MFMA tiles)
#define NBLK     (N_ROWS / RPB)
#define SA       136          // LDS row stride (bf16 elems): 272B, 16B-aligned, spreads banks
#define SB       136

typedef __attribute__((ext_vector_type(8))) short bf16x8;
typedef __attribute__((ext_vector_type(4))) float f32x4;

__device__ inline unsigned short f2bf(float f) {
    unsigned u = __float_as_uint(f);
    return (unsigned short)((u + 0x7FFFu + ((u >> 16) & 1u)) >> 16);
}

__global__ __launch_bounds__(NT, 2) void rqvae_main(
    const float* __restrict__ emb,
    const float* __restrict__ Wenc,   // [128][512]
    const float* __restrict__ Wdec,   // [512][128]
    const float* __restrict__ cb0,    // [256][128]
    const float* __restrict__ cb1,
    const float* __restrict__ cb2,
    float* __restrict__ acc_rq,
    float* __restrict__ acc_recon,
    int* __restrict__ used)           // [3][256]
{
    __shared__ unsigned short s_A[RPB * SA];   // 34816 B : A operand (emb chunk / rem / restored) bf16
    __shared__ unsigned short s_B[128 * SB];   // 34816 B : B operand (Wenc / cb half / Wdec chunk) bf16
    __shared__ float s_cn[3 * K_CODES];        // -0.5*||c||^2, fp32

    const int tid  = threadIdx.x;
    const int wv   = tid >> 6;
    const int lane = tid & 63;
    const int nn   = lane & 15;      // MFMA n / m index
    const int qd   = lane >> 4;      // quad id (0..3)
    const long blkRow = (long)blockIdx.x * RPB;
    const float* cbs[3] = {cb0, cb1, cb2};

    // ---- precompute -0.5*||c_k||^2 in fp32 ----
    for (int i = tid; i < 3 * K_CODES; i += NT) {
        const float4* r = (const float4*)(cbs[i >> 8] + (long)(i & 255) * D_H);
        float s = 0.f;
        #pragma unroll
        for (int d = 0; d < 32; ++d) { float4 v = r[d]; s += v.x*v.x + v.y*v.y + v.z*v.z + v.w*v.w; }
        s_cn[i] = -0.5f * s;
    }

    // rem / res accumulators in MFMA C-layout: [row-tile][col-tile][reg]
    // element (row = wv*32 + rt*16 + qd*4 + e, col = ct*16 + nn)
    f32x4 rem[2][8], res[2][8];
    #pragma unroll
    for (int rt = 0; rt < 2; ++rt)
        #pragma unroll
        for (int ct = 0; ct < 8; ++ct) { rem[rt][ct] = {0.f,0.f,0.f,0.f}; res[rt][ct] = {0.f,0.f,0.f,0.f}; }

    // ---- Phase 1: latent = emb @ Wenc^T  (K=512, 4 chunks of 128) ----
    for (int kc = 0; kc < 4; ++kc) {
        __syncthreads();
        #pragma unroll
        for (int it = 0; it < 16; ++it) {
            const int g = tid + it * NT;            // 0..4095 float4 slots
            const int row = g >> 5, c4 = g & 31;    // 32 float4 per 128-col row
            float4 v = *(const float4*)(emb + (blkRow + row) * D_IN + kc * 128 + c4 * 4);
            *(ushort4*)&s_A[row * SA + c4 * 4] = make_ushort4(f2bf(v.x), f2bf(v.y), f2bf(v.z), f2bf(v.w));
            float4 w = *(const float4*)(Wenc + (long)row * D_IN + kc * 128 + c4 * 4);
            *(ushort4*)&s_B[row * SB + c4 * 4] = make_ushort4(f2bf(w.x), f2bf(w.y), f2bf(w.z), f2bf(w.w));
        }
        __syncthreads();
        #pragma unroll
        for (int rt = 0; rt < 2; ++rt) {
            const int arow = wv * 32 + rt * 16 + nn;
            bf16x8 af[4];
            #pragma unroll
            for (int ks = 0; ks < 4; ++ks) af[ks] = *(const bf16x8*)&s_A[arow * SA + ks * 32 + qd * 8];
            #pragma unroll
            for (int ct = 0; ct < 8; ++ct)
                #pragma unroll
                for (int ks = 0; ks < 4; ++ks) {
                    bf16x8 bf = *(const bf16x8*)&s_B[(ct * 16 + nn) * SB + ks * 32 + qd * 8];
                    rem[rt][ct] = __builtin_amdgcn_mfma_f32_16x16x32_bf16(af[ks], bf, rem[rt][ct], 0, 0, 0);
                }
        }
    }

    // write rem (= latent) bf16 into s_A rows (wave-local; A-layout for stage-0 scores)
    #pragma unroll
    for (int rt = 0; rt < 2; ++rt)
        #pragma unroll
        for (int ct = 0; ct < 8; ++ct)
            #pragma unroll
            for (int e = 0; e < 4; ++e)
                s_A[(wv * 32 + rt * 16 + qd * 4 + e) * SA + ct * 16 + nn] = f2bf(rem[rt][ct][e]);

    // ---- Phase 2: three RQ stages ----
    float local_rq = 0.f;
    for (int t = 0; t < 3; ++t) {
        const float* __restrict__ cb = cbs[t];
        float bv[2][4]; int bi[2][4];
        #pragma unroll
        for (int rt = 0; rt < 2; ++rt)
            #pragma unroll
            for (int e = 0; e < 4; ++e) { bv[rt][e] = -3.402823466e38f; bi[rt][e] = 0; }

        for (int half = 0; half < 2; ++half) {
            __syncthreads();
            #pragma unroll
            for (int it = 0; it < 16; ++it) {
                const int g = tid + it * NT;
                const int row = g >> 5, c4 = g & 31;
                float4 v = *(const float4*)(cb + (long)(half * 128 + row) * D_H + c4 * 4);
                *(ushort4*)&s_B[row * SB + c4 * 4] = make_ushort4(f2bf(v.x), f2bf(v.y), f2bf(v.z), f2bf(v.w));
            }
            __syncthreads();
            #pragma unroll
            for (int rt = 0; rt < 2; ++rt) {
                const int arow = wv * 32 + rt * 16 + nn;
                bf16x8 af[4];
                #pragma unroll
                for (int ks = 0; ks < 4; ++ks) af[ks] = *(const bf16x8*)&s_A[arow * SA + ks * 32 + qd * 8];
                f32x4 sc[8];
                #pragma unroll
                for (int ct = 0; ct < 8; ++ct) sc[ct] = {0.f,0.f,0.f,0.f};
                #pragma unroll
                for (int ct = 0; ct < 8; ++ct)
                    #pragma unroll
                    for (int ks = 0; ks < 4; ++ks) {
                        bf16x8 bf = *(const bf16x8*)&s_B[(ct * 16 + nn) * SB + ks * 32 + qd * 8];
                        sc[ct] = __builtin_amdgcn_mfma_f32_16x16x32_bf16(af[ks], bf, sc[ct], 0, 0, 0);
                    }
                #pragma unroll
                for (int ct = 0; ct < 8; ++ct) {
                    const int code = half * 128 + ct * 16 + nn;
                    const float cn = s_cn[t * K_CODES + code];
                    #pragma unroll
                    for (int e = 0; e < 4; ++e) {
                        const float val = sc[ct][e] + cn;
                        if (val > bv[rt][e] || (val == bv[rt][e] && code < bi[rt][e])) {
                            bv[rt][e] = val; bi[rt][e] = code;
                        }
                    }
                }
            }
        }
        // quad-level argmax reduce (16 lanes per quad hold all 256 candidates per row)
        #pragma unroll
        for (int rt = 0; rt < 2; ++rt)
            #pragma unroll
            for (int e = 0; e < 4; ++e) {
                float v = bv[rt][e]; int i0 = bi[rt][e];
                #pragma unroll
                for (int m = 8; m >= 1; m >>= 1) {
                    const float ov = __shfl_xor(v, m);
                    const int   oi = __shfl_xor(i0, m);
                    if (ov > v || (ov == v && oi < i0)) { v = ov; i0 = oi; }
                }
                bi[rt][e] = i0;
            }
        // update rem/res with fp32 codebook rows; accumulate rq
        #pragma unroll
        for (int rt = 0; rt < 2; ++rt) {
            #pragma unroll
            for (int e = 0; e < 4; ++e)
                if (nn == 0) used[t * K_CODES + bi[rt][e]] = 1;
            #pragma unroll
            for (int ct = 0; ct < 8; ++ct)
                #pragma unroll
                for (int e = 0; e < 4; ++e) {
                    const float c = cb[(long)bi[rt][e] * D_H + ct * 16 + nn];
                    const float r = rem[rt][ct][e] - c;
                    rem[rt][ct][e] = r;
                    res[rt][ct][e] += c;
                    local_rq += r * r;
                    if (t < 2)
                        s_A[(wv * 32 + rt * 16 + qd * 4 + e) * SA + ct * 16 + nn] = f2bf(r);
                }
        }
    }

    // restored -> s_A (A operand for recon)
    #pragma unroll
    for (int rt = 0; rt < 2; ++rt)
        #pragma unroll
        for (int ct = 0; ct < 8; ++ct)
            #pragma unroll
            for (int e = 0; e < 4; ++e)
                s_A[(wv * 32 + rt * 16 + qd * 4 + e) * SA + ct * 16 + nn] = f2bf(res[rt][ct][e]);

    // ---- Phase 3: recon = restored @ Wdec^T, diff vs fp32 emb ----
    float local_rec = 0.f;
    for (int c = 0; c < 4; ++c) {
        __syncthreads();
        #pragma unroll
        for (int it = 0; it < 16; ++it) {
            const int g = tid + it * NT;
            const int row = g >> 5, c4 = g & 31;
            float4 v = *(const float4*)(Wdec + (long)(c * 128 + row) * D_H + c4 * 4);
            *(ushort4*)&s_B[row * SB + c4 * 4] = make_ushort4(f2bf(v.x), f2bf(v.y), f2bf(v.z), f2bf(v.w));
        }
        __syncthreads();
        #pragma unroll
        for (int rt = 0; rt < 2; ++rt) {
            const int arow = wv * 32 + rt * 16 + nn;
            bf16x8 af[4];
            #pragma unroll
            for (int ks = 0; ks < 4; ++ks) af[ks] = *(const bf16x8*)&s_A[arow * SA + ks * 32 + qd * 8];
            f32x4 rc[8];
            #pragma unroll
            for (int ct = 0; ct < 8; ++ct) rc[ct] = {0.f,0.f,0.f,0.f};
            #pragma unroll
            for (int ct = 0; ct < 8; ++ct)
                #pragma unroll
                for (int ks = 0; ks < 4; ++ks) {
                    bf16x8 bf = *(const bf16x8*)&s_B[(ct * 16 + nn) * SB + ks * 32 + qd * 8];
                    rc[ct] = __builtin_amdgcn_mfma_f32_16x16x32_bf16(af[ks], bf, rc[ct], 0, 0, 0);
                }
            #pragma unroll
            for (int ct = 0; ct < 8; ++ct)
                #pragma unroll
                for (int e = 0; e < 4; ++e) {
                    const long row = blkRow + wv * 32 + rt * 16 + qd * 4 + e;
                    const float ev = emb[row * D_IN + c * 128 + ct * 16 + nn];
                    const float d = rc[ct][e] - ev;
                    local_rec += d * d;
                }
        }
    }

    // ---- reduce: wave shuffle, one atomic pair per wave ----
    float r1 = local_rq, r2 = local_rec;
    #pragma unroll
    for (int m = 32; m >= 1; m >>= 1) { r1 += __shfl_xor(r1, m); r2 += __shfl_xor(r2, m); }
    if (lane == 0) { atomicAdd(acc_rq, r1); atomicAdd(acc_recon, r2); }
}

__global__ void rqvae_finalize(const float* __restrict__ acc,
                               const int* __restrict__ used,
                               float* __restrict__ out)
{
    __shared__ int s_sum[4];
    const int tid = threadIdx.x;
    for (int t = 0; t < 3; ++t) {
        int v = (used[t * K_CODES + tid] != 0) ? 1 : 0;
        #pragma unroll
        for (int off = 32; off >= 1; off >>= 1) v += __shfl_down(v, off);
        if ((tid & 63) == 0) s_sum[tid >> 6] = v;
        __syncthreads();
        if (tid == 0) out[3 + t] = (float)(s_sum[0] + s_sum[1] + s_sum[2] + s_sum[3]);
        __syncthreads();
    }
    if (tid == 0) {
        const float rq    = 1.25f * acc[0] / ((float)N_ROWS * 128.0f);
        const float recon =         acc[1] / ((float)N_ROWS * 512.0f);
        out[0] = recon + rq;
        out[1] = recon;
        out[2] = rq;
    }
}

extern "C" void kernel_launch(void* const* d_in, const int* in_sizes, int n_in,
                              void* d_out, int out_size, void* d_ws, size_t ws_size,
                              hipStream_t stream) {
    const float* emb  = (const float*)d_in[0];
    const float* Wenc = (const float*)d_in[1];
    const float* Wdec = (const float*)d_in[2];
    const float* cb0  = (const float*)d_in[3];
    const float* cb1  = (const float*)d_in[4];
    const float* cb2  = (const float*)d_in[5];

    float* ws_f = (float*)d_ws;          // [0]=rq_sum, [1]=recon_sum
    int*   used = (int*)d_ws + 16;       // 3*256 flags

    hipMemsetAsync(d_ws, 0, (16 + 3 * K_CODES) * sizeof(int), stream);
    rqvae_main<<<NBLK, NT, 0, stream>>>(
        emb, Wenc, Wdec, cb0, cb1, cb2, ws_f + 0, ws_f + 1, used);
    rqvae_finalize<<<1, K_CODES, 0, stream>>>(ws_f, used, (float*)d_out);
}